// Round 10
// baseline (449.628 us; speedup 1.0000x reference)
//
#include <hip/hip_runtime.h>
#include <math.h>

#define NB 512
#define NS 1024
#define NT 52
#define TAG_START 50
#define TAG_END 51
#define TILE 32                 // steps per LDS emission tile
#define TILE_BYTES (TILE * NT * 4)   // 6656
#define LDS_TILE_F 1792              // 7168 B per buffer (7 x 1KB staging chunks)

typedef float f4 __attribute__((ext_vector_type(4)));
typedef __attribute__((address_space(1))) const unsigned int gu32;
typedef __attribute__((address_space(3))) unsigned int lu32;

__device__ __forceinline__ float lane_bcast(float x, int l) {
  return __int_as_float(__builtin_amdgcn_readlane(__float_as_int(x), l));
}

// Evidence trail:
//  r1/r6/r7 (~480us, VGPR 44, VALUBusy 8%): M=exp(trans) rematerialized
//    in-loop. FIXED r8 via asm pin (VGPR 64, -68us). Keep the pin.
//  r8 (415us, VALUBusy 9.4%): emission-load latency exposed (depth-1
//    prefetch). FIXED r9 via double-buffered LDS tiles + counted vmcnt
//    (-160us; FETCH unchanged, conflicts negligible).
//  r9 (255us, VALUBusy 15.5%): 600 cyc/step, only ~93 cyc VALU issue
//    (= the 52 FMAs alone). Diagnosis: v_readlane->SGPR->v_fmac hazard
//    wait-states, ~5-8 cyc x 52 pairs/step. r10: broadcast w via LDS
//    same-address ds_read_b128 (VGPR operands, no SGPR round-trip).
extern "C" __global__ void __launch_bounds__(64, 1)
crf_batch_kernel(const float* __restrict__ feats,
                 const unsigned char* __restrict__ mask_u8,
                 const int* __restrict__ tags,
                 const float* __restrict__ trans,
                 double* __restrict__ scores)
{
  __shared__ __align__(16) float emlds[2 * LDS_TILE_F];   // 14336 B
  __shared__ __align__(16) float ldsw[64];                // state broadcast
  const int b = blockIdx.x;
  const int lane = threadIdx.x;

  // ---- detect mask dtype: bool (1 byte) vs int32 (4 byte) ----
  int bad = 0;
  for (int i = lane; i < NB; i += 64) bad |= (mask_u8[(size_t)i * NS] != 1u);
  const bool int_mode = (__any(bad) != 0);

  // ---- sequence length of row b (prefix mask sum) ----
  int len = 0;
  if (int_mode) {
    const int* mi = (const int*)mask_u8;
    for (int s = lane; s < NS; s += 64) len += mi[b * NS + s];
  } else {
    for (int s = lane; s < NS; s += 64) len += (int)mask_u8[b * NS + s];
  }
  #pragma unroll
  for (int off = 32; off > 0; off >>= 1) len += __shfl_xor(len, off, 64);

  // ---- column j of M = exp(transitions), 13 named f32x4, asm-pinned ----
  const int j = (lane < NT) ? lane : 0;
  const float* tj = trans + j;
#define LDM(p)                                   \
  f4 M##p;                                       \
  M##p.x = __expf(tj[(4 * (p) + 0) * NT]);       \
  M##p.y = __expf(tj[(4 * (p) + 1) * NT]);       \
  M##p.z = __expf(tj[(4 * (p) + 2) * NT]);       \
  M##p.w = __expf(tj[(4 * (p) + 3) * NT]);
  LDM(0) LDM(1) LDM(2) LDM(3) LDM(4) LDM(5) LDM(6)
  LDM(7) LDM(8) LDM(9) LDM(10) LDM(11) LDM(12)
#undef LDM
  asm volatile("" : "+v"(M0), "+v"(M1), "+v"(M2), "+v"(M3), "+v"(M4),
                    "+v"(M5), "+v"(M6), "+v"(M7), "+v"(M8), "+v"(M9),
                    "+v"(M10), "+v"(M11), "+v"(M12));

  const float* fb = feats + (size_t)b * NS * NT;
  // clamp for the 512B staging overrun of the last tile (b==511 would fault)
  const char* gclamp = (const char*)feats + (size_t)NB * NS * NT * 4 - 16;

  // stage tile t (7 x 1KB) into LDS buffer `par`
#define STAGE(t, par) do {                                                  \
    const char* _gb = (const char*)fb + (size_t)(t) * TILE_BYTES;           \
    float* _lb = emlds + (par) * LDS_TILE_F;                                \
    _Pragma("unroll")                                                       \
    for (int _k = 0; _k < 7; ++_k) {                                        \
      const char* _gp = _gb + _k * 1024 + lane * 16;                        \
      if (_gp > gclamp) _gp = gclamp;                                       \
      __builtin_amdgcn_global_load_lds((gu32*)_gp, (lu32*)(_lb + _k * 256), \
                                       16, 0, 0);                           \
    }                                                                       \
  } while (0)

  // ---- init (s = 0) ----
  float p0 = (lane < NT) ? (fb[lane] + trans[TAG_START * NT + lane]) : -1e30f;
  float c0 = p0;
  #pragma unroll
  for (int off = 32; off > 0; off >>= 1) c0 = fmaxf(c0, __shfl_xor(c0, off, 64));
  float w = (lane < NT) ? __expf(p0 - c0) : 0.f;
  int kacc = 6 * (len - 1);   // hoisted per-step 2^-6; renorm Ks added below

  const f4* lvv = (const f4*)ldsw;   // same-address broadcast reads
#define B4(p)                              \
  {                                        \
    f4 vb = lvv[p];                        \
    acc0 = fmaf(vb.x, M##p.x, acc0);       \
    acc1 = fmaf(vb.y, M##p.y, acc1);       \
    acc2 = fmaf(vb.z, M##p.z, acc2);       \
    acc3 = fmaf(vb.w, M##p.w, acc3);       \
  }

  // ---- forward recursion over double-buffered 32-step tiles ----
  const int Tt = (len + TILE - 1) / TILE;
  STAGE(0, 0);
  STAGE(1, 1);
  bool pend7 = true;
  int s = 1;
  for (int t = 0; t < Tt; ++t) {
    if (pend7) asm volatile("s_waitcnt vmcnt(7)" ::: "memory");
    else       asm volatile("s_waitcnt vmcnt(0)" ::: "memory");

    const float* bufX = emlds + (t & 1) * LDS_TILE_F;
    const int s0 = t * TILE;
    const int locF = s - s0;                    // 1 for t==0, else 0
    const int locE = min(TILE - 1, len - 1 - s0);

    // refill the 2-deep emission pipeline from this tile
    float emA = bufX[locF * NT + j];
    float efs = __expf(emA) * 0.015625f;        // exp(em)*2^-6, exact pow2
    emA = bufX[min(locF + 1, TILE - 1) * NT + j];

    for (int loc = locF; loc <= locE; ++loc, ++s) {
      // broadcast state: 1 ds_write + 13 same-address ds_read_b128.
      // Single-wave in-order DS pipe makes write->read correct without a
      // barrier; next iteration's write depends on this one's reads (WAR
      // ordered by dataflow).
      ldsw[lane] = w;

      float ef = efs;
      efs = __expf(emA) * 0.015625f;            // for step s+1
      emA = bufX[min(loc + 2, TILE - 1) * NT + j];  // 2 ahead

      float acc0 = 0.f, acc1 = 0.f, acc2 = 0.f, acc3 = 0.f;
      B4(0) B4(1) B4(2) B4(3) B4(4) B4(5) B4(6)
      B4(7) B4(8) B4(9) B4(10) B4(11) B4(12)
      float nv = ef * ((acc0 + acc1) + (acc2 + acc3));

      if ((s & 3) == 0) {      // exact pow2 re-center on lane 0's exponent
        float n0 = lane_bcast(nv, 0);
        int K = ((__float_as_int(n0) >> 23) & 0xff) - 127;
        nv = nv * __int_as_float((127 - K) << 23);
        kacc += K;
      }
      w = nv;
    }

    pend7 = (t + 2 < NS / TILE) && ((t + 2) * TILE < len);
    if (pend7) STAGE(t + 2, t & 1);
  }

  // ---- final: forward_b = c0 + kacc*ln2 + log(sum_i w[i] * M[i][END]) ----
  {
    ldsw[lane] = w;
    float acc0 = 0.f, acc1 = 0.f, acc2 = 0.f, acc3 = 0.f;
    B4(0) B4(1) B4(2) B4(3) B4(4) B4(5) B4(6)
    B4(7) B4(8) B4(9) B4(10) B4(11) B4(12)
    float fin  = __logf((acc0 + acc1) + (acc2 + acc3));  // valid on lane END
    float finU = lane_bcast(fin, TAG_END);
    double fwd = (double)c0 + (double)kacc * 0.6931471805599453 + (double)finU;

    // ---- gold path score ----
    float g = 0.f;
    for (int sg = lane; sg < len; sg += 64) {
      int tg = tags[b * NS + sg];
      int pv = (sg == 0) ? TAG_START : tags[b * NS + sg - 1];
      g += fb[sg * NT + tg] + trans[pv * NT + tg];
    }
    #pragma unroll
    for (int off = 32; off > 0; off >>= 1) g += __shfl_xor(g, off, 64);
    int lastTag = tags[b * NS + (len - 1)];
    double gold = (double)g + (double)trans[lastTag * NT + TAG_END];

    if (lane == 0) scores[b] = fwd - gold;
  }
#undef B4
#undef STAGE
}

extern "C" __global__ void __launch_bounds__(512)
crf_reduce_kernel(const double* __restrict__ scores, float* __restrict__ out)
{
  __shared__ double sh[8];
  int t = threadIdx.x;
  double x = scores[t];
  #pragma unroll
  for (int off = 32; off > 0; off >>= 1) x += __shfl_xor(x, off, 64);
  if ((t & 63) == 0) sh[t >> 6] = x;
  __syncthreads();
  if (t == 0) {
    double tot = 0.0;
    #pragma unroll
    for (int wv = 0; wv < 8; ++wv) tot += sh[wv];
    out[0] = (float)tot;
  }
}

extern "C" void kernel_launch(void* const* d_in, const int* in_sizes, int n_in,
                              void* d_out, int out_size, void* d_ws, size_t ws_size,
                              hipStream_t stream) {
  const float*         feats = (const float*)d_in[0];
  const unsigned char* mask  = (const unsigned char*)d_in[1];
  const int*           tags  = (const int*)d_in[2];
  const float*         trans = (const float*)d_in[3];
  double* scores = (double*)d_ws;   // 512 doubles = 4 KB scratch

  crf_batch_kernel<<<NB, 64, 0, stream>>>(feats, mask, tags, trans, scores);
  crf_reduce_kernel<<<1, 512, 0, stream>>>(scores, (float*)d_out);
}